// Round 11
// baseline (353.410 us; speedup 1.0000x reference)
//
#include <hip/hip_runtime.h>
#include <hip/hip_bf16.h>

#define B_ 32
#define T_ 64
#define H_ 128
#define L3OUT 54
#define FLAT_ 1728

typedef __attribute__((ext_vector_type(8))) short bf16x8;
typedef __attribute__((ext_vector_type(4))) float f32x4;

__device__ __forceinline__ float leakyf(float v) { return v > 0.f ? v : 0.01f * v; }
__device__ __forceinline__ float sigmoidf_(float v) { return 1.f / (1.f + expf(-v)); }
__device__ __forceinline__ unsigned int bf16rne(float v) {
  unsigned int b = __float_as_uint(v);
  return (b + 0x7FFFu + ((b >> 16) & 1u)) >> 16;
}
__device__ __forceinline__ bf16x8 ldb8(const unsigned short* p) {
  return *(const bf16x8*)p;
}

// ---------------------------------------------------------------------------
// Kernel 0: weight prep + transposes. (unchanged)
// ---------------------------------------------------------------------------
__global__ __launch_bounds__(256) void k_prep(
    const float* __restrict__ w1, const float* __restrict__ w2,
    const float* __restrict__ w3, const float* __restrict__ linw,
    const float* __restrict__ wih0, const float* __restrict__ whh0,
    const float* __restrict__ wih1, const float* __restrict__ whh1,
    unsigned short* __restrict__ w1eh, unsigned short* __restrict__ w1el,
    unsigned short* __restrict__ w2h, unsigned short* __restrict__ w2l,
    unsigned short* __restrict__ w3h, unsigned short* __restrict__ w3l,
    unsigned short* __restrict__ linwh, unsigned short* __restrict__ linwl,
    unsigned short* __restrict__ wih0h, unsigned short* __restrict__ wih0l,
    float* __restrict__ whh0T, float* __restrict__ wih1T,
    float* __restrict__ whh1T) {
  const int e = blockIdx.x * 256 + threadIdx.x;
  if (e >= 264960) {
    int e5 = e - 264960;
    int m = e5 >> 16, r = e5 & 65535;
    int k = r >> 9, j = r & 511;
    const float* src = (m == 0) ? whh0 : ((m == 1) ? wih1 : whh1);
    float* dst = (m == 0) ? whh0T : ((m == 1) ? wih1T : whh1T);
    dst[r] = src[j * 128 + k];
    return;
  }
  float v;
  unsigned short* dh;
  unsigned short* dl;
  int di;
  if (e < 20480) {
    int cc = e / 5120, rem = e - cc * 5120;
    int c2 = rem / 160, r = rem - c2 * 160;
    int tap = r >> 5, c1l = r & 31;
    v = w2[c2 * 640 + (cc * 32 + c1l) * 5 + tap];
    dh = w2h; dl = w2l; di = e;
  } else if (e < 25600) {
    int e2 = e - 20480;
    int c3 = e2 / 160, r = e2 - c3 * 160;
    int tap = r >> 5, c2 = r & 31;
    v = w3[c3 * 160 + c2 * 5 + tap];
    dh = w3h; dl = w3l; di = e2;
  } else if (e < 198400) {
    int e3 = e - 25600;
    v = linw[e3];
    dh = linwh; dl = linwl; di = e3;
  } else if (e < 263936) {
    int e4 = e - 198400;
    int g = e4 >> 7, k = e4 & 127;
    v = (k < 100) ? wih0[g * 100 + k] : 0.f;
    dh = wih0h; dl = wih0l; di = e4;
  } else {
    int i = e - 263936;
    int c1 = i >> 3, j = i & 7;
    v = (j < 5) ? w1[c1 * 5 + j] : 0.f;
    dh = w1eh; dl = w1el; di = i;
  }
  unsigned int hb = bf16rne(v);
  float hf = __uint_as_float(hb << 16);
  unsigned int lb = bf16rne(v - hf);
  dh[di] = (unsigned short)hb;
  dl[di] = (unsigned short)lb;
}

// ---------------------------------------------------------------------------
// Kernel 1: conv1 (fp32, thread=position) + conv2 (MFMA) + conv3 (MFMA).
// NEW: 2 blocks per n (grid 2x2048, 448 thr). Block h:
//   positions P0=288h .. P0+NPOS-1 (NPOS 338/212), X offset 864h,
//   conv2 n-tiles {h?6+w:w | w<NT2} (NT2 7/5), conv3 l3-tiles {2h+w | w<2}.
// Index identities (h-independent local addressing):
//   conv2/conv3 B row = 48w + 3*l15 + tap ; A3 row (l2 local) = 16w + l15.
// LDS = 4 KB Xs + 28.2 KB AhU = 32.2 KB -> 4 blocks/CU, 28 waves/CU.
// Duplicated conv1 work: pos 288..337 only (+10%). Numerics identical.
// ---------------------------------------------------------------------------
__global__ __launch_bounds__(448) void k_conv123(
    const float* __restrict__ X, const float* __restrict__ w1,
    const unsigned short* __restrict__ w2h, const unsigned short* __restrict__ w2l,
    const unsigned short* __restrict__ w3h, const unsigned short* __restrict__ w3l,
    unsigned short* __restrict__ s3g) {
  __shared__ __align__(16) float Xs[1024];
  __shared__ __align__(16) unsigned int AhU[352 * 20];  // rows=local pos / l2

  const int h = blockIdx.x;
  const int n = blockIdx.y;
  const int tid = threadIdx.x;
  const int lane = tid & 63;
  const int w = tid >> 6;        // 0..6
  const int l15 = lane & 15;
  const int cg = lane >> 4;
  const int NPOS = h ? 212 : 338;
  const int NT2 = h ? 5 : 7;

  const float* Xn = X + (size_t)n * 1500 + 864 * h;
  for (int i = tid; i < 1024; i += 448)
    Xs[i] = (864 * h + i < 1500) ? Xn[i] : 0.f;
  // zero pad rows NPOS..351 once (conv2/conv3 read them for discarded cols)
  for (int i = tid + NPOS * 20; i < 7040; i += 448) AhU[i] = 0u;

  f32x4 acc2[2];
  acc2[0] = (f32x4){0.f, 0.f, 0.f, 0.f};
  acc2[1] = (f32x4){0.f, 0.f, 0.f, 0.f};

  for (int cc = 0; cc < 4; ++cc) {  // 4 chunks of 32 c1
    __syncthreads();                // previous chunk's conv2 reads done
    // ---- conv1 fp32: thread = local position, all 32 c1 of chunk ----
    if (tid < NPOS) {
      const float* xp = Xs + 3 * tid;
      float x0 = xp[0], x1 = xp[1], x2 = xp[2], x3 = xp[3], x4 = xp[4];
      const float* wc = w1 + cc * 160;  // uniform -> scalar loads
      unsigned int rowbuf[16];
#pragma unroll
      for (int p = 0; p < 16; ++p) {
        const float* wa = wc + 10 * p;
        float vA = fmaf(x4, wa[4], fmaf(x3, wa[3], fmaf(x2, wa[2], fmaf(x1, wa[1], x0 * wa[0]))));
        float vB = fmaf(x4, wa[9], fmaf(x3, wa[8], fmaf(x2, wa[7], fmaf(x1, wa[6], x0 * wa[5]))));
        vA = fmaxf(vA, 0.01f * vA);
        vB = fmaxf(vB, 0.01f * vB);
        rowbuf[p] = bf16rne(vA) | (bf16rne(vB) << 16);
      }
#pragma unroll
      for (int q = 0; q < 4; ++q)
        *(uint4*)(&AhU[tid * 20 + 4 * q]) = *(uint4*)(&rowbuf[4 * q]);
    }
    __syncthreads();
    // ---- conv2 MFMA: wave w = one n-tile ----
    if (w < NT2) {
      const unsigned short* w2hB = w2h + cc * 5120;
      const unsigned short* w2lB = w2l + cc * 5120;
#pragma unroll
      for (int tap = 0; tap < 5; ++tap) {
        const int wc = tap * 32 + cg * 8;
        bf16x8 ah0 = ldb8(w2hB + l15 * 160 + wc);
        bf16x8 ah1 = ldb8(w2hB + (l15 + 16) * 160 + wc);
        bf16x8 al0 = ldb8(w2lB + l15 * 160 + wc);
        bf16x8 al1 = ldb8(w2lB + (l15 + 16) * 160 + wc);
        int row = 48 * w + 3 * l15 + tap;
        bf16x8 bfr = ldb8((const unsigned short*)AhU + row * 40 + cg * 8);
        acc2[0] = __builtin_amdgcn_mfma_f32_16x16x32_bf16(ah0, bfr, acc2[0], 0, 0, 0);
        acc2[0] = __builtin_amdgcn_mfma_f32_16x16x32_bf16(al0, bfr, acc2[0], 0, 0, 0);
        acc2[1] = __builtin_amdgcn_mfma_f32_16x16x32_bf16(ah1, bfr, acc2[1], 0, 0, 0);
        acc2[1] = __builtin_amdgcn_mfma_f32_16x16x32_bf16(al1, bfr, acc2[1], 0, 0, 0);
      }
    }
  }
  __syncthreads();  // all conv2 reads of AhU done
  // ---- A3 (aliases AhU): rows = local l2 = 16w + l15 ----
  if (h) {  // zero local l2 rows 80..98 (conv3 tile-3 pad reads)
    for (int i = tid; i < 380; i += 448) AhU[1600 + i] = 0u;
  }
  if (w < NT2) {
    int l2l = 16 * w + l15;
#pragma unroll
    for (int mt = 0; mt < 2; ++mt) {
#pragma unroll
      for (int j = 0; j < 2; ++j) {
        float e0 = leakyf(acc2[mt][2 * j]);
        float e1 = leakyf(acc2[mt][2 * j + 1]);
        AhU[l2l * 20 + mt * 8 + cg * 2 + j] = bf16rne(e0) | (bf16rne(e1) << 16);
      }
    }
  }
  __syncthreads();
  // ---- conv3 MFMA: waves 0,1 -> l3-tile tt = 2h + w ----
  if (w < 2) {
    f32x4 a3[2];
    a3[0] = (f32x4){0.f, 0.f, 0.f, 0.f};
    a3[1] = (f32x4){0.f, 0.f, 0.f, 0.f};
#pragma unroll
    for (int tap = 0; tap < 5; ++tap) {
      const int wc = tap * 32 + cg * 8;
      bf16x8 wh0 = ldb8(w3h + l15 * 160 + wc);
      bf16x8 wh1 = ldb8(w3h + (l15 + 16) * 160 + wc);
      bf16x8 wl0 = ldb8(w3l + l15 * 160 + wc);
      bf16x8 wl1 = ldb8(w3l + (l15 + 16) * 160 + wc);
      int row = 48 * w + 3 * l15 + tap;
      bf16x8 bfr = ldb8((const unsigned short*)AhU + row * 40 + cg * 8);
      a3[0] = __builtin_amdgcn_mfma_f32_16x16x32_bf16(wh0, bfr, a3[0], 0, 0, 0);
      a3[0] = __builtin_amdgcn_mfma_f32_16x16x32_bf16(wl0, bfr, a3[0], 0, 0, 0);
      a3[1] = __builtin_amdgcn_mfma_f32_16x16x32_bf16(wh1, bfr, a3[1], 0, 0, 0);
      a3[1] = __builtin_amdgcn_mfma_f32_16x16x32_bf16(wl1, bfr, a3[1], 0, 0, 0);
    }
    int l3 = 32 * h + 16 * w + l15;
    if (l3 < L3OUT) {
#pragma unroll
      for (int mt = 0; mt < 2; ++mt) {
#pragma unroll
        for (int r = 0; r < 4; ++r) {
          int c3 = mt * 16 + cg * 4 + r;
          s3g[(size_t)n * FLAT_ + c3 * L3OUT + l3] = (unsigned short)bf16rne(leakyf(a3[mt][r]));
        }
      }
    }
  }
}

// ---------------------------------------------------------------------------
// Kernel 2: FUSED fe + xg0. (unchanged from round 10)
// ---------------------------------------------------------------------------
__global__ __launch_bounds__(448) void k_gemm_fx(
    const unsigned short* __restrict__ s3g,
    const unsigned short* __restrict__ linwh, const unsigned short* __restrict__ linwl,
    const unsigned short* __restrict__ wih0h, const unsigned short* __restrict__ wih0l,
    float* __restrict__ xg0) {
  __shared__ __align__(16) unsigned short fehS[16][136];
  __shared__ __align__(16) unsigned short felS[16][136];

  const int m0 = blockIdx.x * 16;
  const int tid = threadIdx.x;
  const int lane = tid & 63;
  const int w = tid >> 6;
  const int l15 = lane & 15;
  const int cg = lane >> 4;

  if (tid < 192) {
    int r = tid / 12, c = tid - r * 12;
    ((unsigned int*)&fehS[r][112])[c] = 0u;
    ((unsigned int*)&felS[r][112])[c] = 0u;
  }

  int brow = w * 16 + l15;
  if (brow > 99) brow = 99;
  const unsigned short* ap = s3g + (size_t)(m0 + l15) * FLAT_ + cg * 8;
  const unsigned short* bhp = linwh + (size_t)brow * FLAT_ + cg * 8;
  const unsigned short* blp = linwl + (size_t)brow * FLAT_ + cg * 8;

  f32x4 acc = (f32x4){0.f, 0.f, 0.f, 0.f};
#pragma unroll 6
  for (int ks = 0; ks < 54; ++ks) {
    bf16x8 af = ldb8(ap + ks * 32);
    bf16x8 bh = ldb8(bhp + ks * 32);
    bf16x8 bl = ldb8(blp + ks * 32);
    acc = __builtin_amdgcn_mfma_f32_16x16x32_bf16(af, bh, acc, 0, 0, 0);
    acc = __builtin_amdgcn_mfma_f32_16x16x32_bf16(af, bl, acc, 0, 0, 0);
  }
  const int jcol = w * 16 + l15;
#pragma unroll
  for (int r = 0; r < 4; ++r) {
    float v = acc[r];
    unsigned int hb = bf16rne(v);
    float hf = __uint_as_float(hb << 16);
    unsigned int lb = bf16rne(v - hf);
    fehS[cg * 4 + r][jcol] = (unsigned short)hb;
    felS[cg * 4 + r][jcol] = (unsigned short)lb;
  }
  __syncthreads();

#pragma unroll
  for (int nt0 = 0; nt0 < 5; ++nt0) {
    int nt = w + 7 * nt0;
    if (nt < 32) {
      f32x4 a = (f32x4){0.f, 0.f, 0.f, 0.f};
#pragma unroll
      for (int ks = 0; ks < 4; ++ks) {
        bf16x8 ah = ldb8(&fehS[l15][ks * 32 + cg * 8]);
        bf16x8 al = ldb8(&felS[l15][ks * 32 + cg * 8]);
        int br = nt * 16 + l15;
        bf16x8 bh = ldb8(wih0h + (size_t)br * 128 + ks * 32 + cg * 8);
        bf16x8 bl = ldb8(wih0l + (size_t)br * 128 + ks * 32 + cg * 8);
        a = __builtin_amdgcn_mfma_f32_16x16x32_bf16(ah, bh, a, 0, 0, 0);
        a = __builtin_amdgcn_mfma_f32_16x16x32_bf16(ah, bl, a, 0, 0, 0);
        a = __builtin_amdgcn_mfma_f32_16x16x32_bf16(al, bh, a, 0, 0, 0);
      }
#pragma unroll
      for (int r = 0; r < 4; ++r)
        xg0[(size_t)(m0 + cg * 4 + r) * 512 + nt * 16 + l15] = a[r];
    }
  }
}

// ---------------------------------------------------------------------------
// Kernel 3: LSTM layer 0 -- K-sliced dot; NEW: x folded into dot phase
// (thread tid loads xg[t*512+tid] coalesced, adds into its own slice
// partial); next-step x prefetched at top of dot phase.
// ---------------------------------------------------------------------------
__global__ __launch_bounds__(512) void k_lstm0(
    const float* __restrict__ xg0, const float* __restrict__ whh0T,
    const int* __restrict__ lengths, float* __restrict__ hs1) {
  __shared__ __align__(16) float h0s[H_];
  __shared__ float ps[16 * 128];
  const int b = blockIdx.x;
  const int tid = threadIdx.x;
  const int ks = tid >> 7;
  const int jj = tid & 127;
  float w[4][32];
#pragma unroll
  for (int kk = 0; kk < 32; ++kk) {
#pragma unroll
    for (int q = 0; q < 4; ++q)
      w[q][kk] = whh0T[(ks * 32 + kk) * 512 + q * 128 + jj];
  }
  if (tid < H_) h0s[tid] = 0.f;
  float c = 0.f;
  const int len = lengths[b];
  float xcur = xg0[(size_t)(b * T_) * 512 + tid];
  __syncthreads();
  for (int t = 0; t < len; ++t) {
    float xnxt = (t + 1 < len) ? xg0[(size_t)(b * T_ + t + 1) * 512 + tid] : 0.f;
    float p0 = 0.f, p1 = 0.f, p2 = 0.f, p3 = 0.f;
#pragma unroll
    for (int k4 = 0; k4 < 8; ++k4) {
      float4 hv = *(const float4*)(h0s + ks * 32 + k4 * 4);
      p0 = fmaf(hv.x, w[0][k4 * 4], fmaf(hv.y, w[0][k4 * 4 + 1], fmaf(hv.z, w[0][k4 * 4 + 2], fmaf(hv.w, w[0][k4 * 4 + 3], p0))));
      p1 = fmaf(hv.x, w[1][k4 * 4], fmaf(hv.y, w[1][k4 * 4 + 1], fmaf(hv.z, w[1][k4 * 4 + 2], fmaf(hv.w, w[1][k4 * 4 + 3], p1))));
      p2 = fmaf(hv.x, w[2][k4 * 4], fmaf(hv.y, w[2][k4 * 4 + 1], fmaf(hv.z, w[2][k4 * 4 + 2], fmaf(hv.w, w[2][k4 * 4 + 3], p2))));
      p3 = fmaf(hv.x, w[3][k4 * 4], fmaf(hv.y, w[3][k4 * 4 + 1], fmaf(hv.z, w[3][k4 * 4 + 2], fmaf(hv.w, w[3][k4 * 4 + 3], p3))));
    }
    p0 += (ks == 0) ? xcur : 0.f;
    p1 += (ks == 1) ? xcur : 0.f;
    p2 += (ks == 2) ? xcur : 0.f;
    p3 += (ks == 3) ? xcur : 0.f;
    ps[(ks * 4 + 0) * 128 + jj] = p0;
    ps[(ks * 4 + 1) * 128 + jj] = p1;
    ps[(ks * 4 + 2) * 128 + jj] = p2;
    ps[(ks * 4 + 3) * 128 + jj] = p3;
    __syncthreads();
    if (tid < H_) {
      float gi = (ps[0 * 128 + jj] + ps[4 * 128 + jj]) + (ps[8 * 128 + jj] + ps[12 * 128 + jj]);
      float gf = (ps[1 * 128 + jj] + ps[5 * 128 + jj]) + (ps[9 * 128 + jj] + ps[13 * 128 + jj]);
      float gg = (ps[2 * 128 + jj] + ps[6 * 128 + jj]) + (ps[10 * 128 + jj] + ps[14 * 128 + jj]);
      float go = (ps[3 * 128 + jj] + ps[7 * 128 + jj]) + (ps[11 * 128 + jj] + ps[15 * 128 + jj]);
      float ig = sigmoidf_(gi);
      float fg = sigmoidf_(gf);
      float gt = tanhf(gg);
      float og = sigmoidf_(go);
      c = fg * c + ig * gt;
      float hn = og * tanhf(c);
      h0s[jj] = hn;
      hs1[((size_t)(b * T_ + t)) * H_ + jj] = hn;
    }
    __syncthreads();
    xcur = xnxt;
  }
}

// ---------------------------------------------------------------------------
// Kernel 4: xg1 = hs1 @ wih1^T. (unchanged)
// ---------------------------------------------------------------------------
__global__ __launch_bounds__(512) void k_xg1(
    const float* __restrict__ hs1, const float* __restrict__ wih1T,
    float* __restrict__ xg1) {
  __shared__ __align__(16) float hsS[8][128];
  const int r0 = blockIdx.x * 8;
  const int tid = threadIdx.x;
  for (int i = tid; i < 8 * 128; i += 512) ((float*)hsS)[i] = hs1[(size_t)r0 * 128 + i];
  __syncthreads();
  float acc[8] = {0.f, 0.f, 0.f, 0.f, 0.f, 0.f, 0.f, 0.f};
#pragma unroll 4
  for (int k4 = 0; k4 < 32; ++k4) {
    float w0 = wih1T[(4 * k4 + 0) * 512 + tid];
    float w1v = wih1T[(4 * k4 + 1) * 512 + tid];
    float w2v = wih1T[(4 * k4 + 2) * 512 + tid];
    float w3v = wih1T[(4 * k4 + 3) * 512 + tid];
#pragma unroll
    for (int i = 0; i < 8; ++i) {
      float4 h = *(const float4*)(&hsS[i][4 * k4]);
      acc[i] += h.x * w0 + h.y * w1v + h.z * w2v + h.w * w3v;
    }
  }
#pragma unroll
  for (int i = 0; i < 8; ++i) xg1[((size_t)(r0 + i)) * 512 + tid] = acc[i];
}

// ---------------------------------------------------------------------------
// Kernel 5: LSTM layer 1 + FC tail -- same x-in-dot refactor.
// ---------------------------------------------------------------------------
__global__ __launch_bounds__(512) void k_lstm1(
    const float* __restrict__ xg1, const float* __restrict__ whh1T,
    const float* __restrict__ fc1, const float* __restrict__ fc2,
    const int* __restrict__ lengths, float* __restrict__ out) {
  __shared__ __align__(16) float h1s[H_];
  __shared__ float ps[16 * 128];
  __shared__ float tmp10[10];
  const int b = blockIdx.x;
  const int tid = threadIdx.x;
  const int ks = tid >> 7;
  const int jj = tid & 127;
  float w[4][32];
#pragma unroll
  for (int kk = 0; kk < 32; ++kk) {
#pragma unroll
    for (int q = 0; q < 4; ++q)
      w[q][kk] = whh1T[(ks * 32 + kk) * 512 + q * 128 + jj];
  }
  if (tid < H_) h1s[tid] = 0.f;
  float c = 0.f;
  const int len = lengths[b];
  float xcur = xg1[(size_t)(b * T_) * 512 + tid];
  __syncthreads();
  for (int t = 0; t < len; ++t) {
    float xnxt = (t + 1 < len) ? xg1[(size_t)(b * T_ + t + 1) * 512 + tid] : 0.f;
    float p0 = 0.f, p1 = 0.f, p2 = 0.f, p3 = 0.f;
#pragma unroll
    for (int k4 = 0; k4 < 8; ++k4) {
      float4 hv = *(const float4*)(h1s + ks * 32 + k4 * 4);
      p0 = fmaf(hv.x, w[0][k4 * 4], fmaf(hv.y, w[0][k4 * 4 + 1], fmaf(hv.z, w[0][k4 * 4 + 2], fmaf(hv.w, w[0][k4 * 4 + 3], p0))));
      p1 = fmaf(hv.x, w[1][k4 * 4], fmaf(hv.y, w[1][k4 * 4 + 1], fmaf(hv.z, w[1][k4 * 4 + 2], fmaf(hv.w, w[1][k4 * 4 + 3], p1))));
      p2 = fmaf(hv.x, w[2][k4 * 4], fmaf(hv.y, w[2][k4 * 4 + 1], fmaf(hv.z, w[2][k4 * 4 + 2], fmaf(hv.w, w[2][k4 * 4 + 3], p2))));
      p3 = fmaf(hv.x, w[3][k4 * 4], fmaf(hv.y, w[3][k4 * 4 + 1], fmaf(hv.z, w[3][k4 * 4 + 2], fmaf(hv.w, w[3][k4 * 4 + 3], p3))));
    }
    p0 += (ks == 0) ? xcur : 0.f;
    p1 += (ks == 1) ? xcur : 0.f;
    p2 += (ks == 2) ? xcur : 0.f;
    p3 += (ks == 3) ? xcur : 0.f;
    ps[(ks * 4 + 0) * 128 + jj] = p0;
    ps[(ks * 4 + 1) * 128 + jj] = p1;
    ps[(ks * 4 + 2) * 128 + jj] = p2;
    ps[(ks * 4 + 3) * 128 + jj] = p3;
    __syncthreads();
    if (tid < H_) {
      float gi = (ps[0 * 128 + jj] + ps[4 * 128 + jj]) + (ps[8 * 128 + jj] + ps[12 * 128 + jj]);
      float gf = (ps[1 * 128 + jj] + ps[5 * 128 + jj]) + (ps[9 * 128 + jj] + ps[13 * 128 + jj]);
      float gg = (ps[2 * 128 + jj] + ps[6 * 128 + jj]) + (ps[10 * 128 + jj] + ps[14 * 128 + jj]);
      float go = (ps[3 * 128 + jj] + ps[7 * 128 + jj]) + (ps[11 * 128 + jj] + ps[15 * 128 + jj]);
      float ig = sigmoidf_(gi);
      float fg = sigmoidf_(gf);
      float gt = tanhf(gg);
      float og = sigmoidf_(go);
      c = fg * c + ig * gt;
      float hn = og * tanhf(c);
      h1s[jj] = hn;
    }
    __syncthreads();
    xcur = xnxt;
  }
  if (tid < 10) {
    const float* fr = fc1 + tid * H_;
    float s = 0.f;
#pragma unroll 4
    for (int k = 0; k < H_; ++k) s += h1s[k] * fr[k];
    tmp10[tid] = leakyf(s);
  }
  __syncthreads();
  if (tid < 2) {
    const float* fr = fc2 + tid * 10;
    float s = 0.f;
#pragma unroll
    for (int j = 0; j < 10; ++j) s += tmp10[j] * fr[j];
    out[b * 2 + tid] = leakyf(s);
  }
}

extern "C" void kernel_launch(void* const* d_in, const int* in_sizes, int n_in,
                              void* d_out, int out_size, void* d_ws, size_t ws_size,
                              hipStream_t stream) {
  const float* X = (const float*)d_in[0];
  const int* lengths = (const int*)d_in[1];
  const float* w1 = (const float*)d_in[2];
  const float* w2 = (const float*)d_in[3];
  const float* w3 = (const float*)d_in[4];
  const float* linw = (const float*)d_in[5];
  const float* wih0 = (const float*)d_in[6];
  const float* whh0 = (const float*)d_in[7];
  const float* wih1 = (const float*)d_in[8];
  const float* whh1 = (const float*)d_in[9];
  const float* fc1 = (const float*)d_in[10];
  const float* fc2 = (const float*)d_in[11];

  char* wsb = (char*)d_ws;
  size_t off = 0;
  auto alloc = [&](size_t bytes) {
    char* p = wsb + off;
    off += (bytes + 511) & ~(size_t)511;
    return p;
  };
  unsigned short* s3g = (unsigned short*)alloc(2048 * 1728 * 2);
  float* xg0 = (float*)alloc(2048 * 512 * 4);
  unsigned short* w1eh = (unsigned short*)alloc(1024 * 2);
  unsigned short* w1el = (unsigned short*)alloc(1024 * 2);
  unsigned short* w2h = (unsigned short*)alloc(20480 * 2);
  unsigned short* w2l = (unsigned short*)alloc(20480 * 2);
  unsigned short* w3h = (unsigned short*)alloc(5120 * 2);
  unsigned short* w3l = (unsigned short*)alloc(5120 * 2);
  unsigned short* linwh = (unsigned short*)alloc(172800 * 2);
  unsigned short* linwl = (unsigned short*)alloc(172800 * 2);
  unsigned short* wih0h = (unsigned short*)alloc(65536 * 2);
  unsigned short* wih0l = (unsigned short*)alloc(65536 * 2);
  float* whh0T = (float*)alloc(65536 * 4);
  float* wih1T = (float*)alloc(65536 * 4);
  float* whh1T = (float*)alloc(65536 * 4);
  float* hs1 = (float*)alloc(262144 * 4);
  float* xg1 = (float*)alloc(2048 * 512 * 4);

  k_prep<<<1803, 256, 0, stream>>>(w1, w2, w3, linw, wih0, whh0, wih1, whh1,
                                   w1eh, w1el, w2h, w2l, w3h, w3l,
                                   linwh, linwl, wih0h, wih0l,
                                   whh0T, wih1T, whh1T);
  k_conv123<<<dim3(2, 2048), 448, 0, stream>>>(X, w1, w2h, w2l, w3h, w3l, s3g);
  k_gemm_fx<<<128, 448, 0, stream>>>(s3g, linwh, linwl, wih0h, wih0l, xg0);
  k_lstm0<<<32, 512, 0, stream>>>(xg0, whh0T, lengths, hs1);
  k_xg1<<<256, 512, 0, stream>>>(hs1, wih1T, xg1);
  k_lstm1<<<32, 512, 0, stream>>>(xg1, whh1T, fc1, fc2, lengths, (float*)d_out);
}

// Round 12
// 267.790 us; speedup vs baseline: 1.3197x; 1.3197x over previous
//
#include <hip/hip_runtime.h>
#include <hip/hip_bf16.h>

#define B_ 32
#define T_ 64
#define H_ 128
#define L3OUT 54
#define FLAT_ 1728

typedef __attribute__((ext_vector_type(8))) short bf16x8;
typedef __attribute__((ext_vector_type(4))) float f32x4;

__device__ __forceinline__ float leakyf(float v) { return v > 0.f ? v : 0.01f * v; }
__device__ __forceinline__ float sigmoidf_(float v) { return 1.f / (1.f + expf(-v)); }
__device__ __forceinline__ unsigned int bf16rne(float v) {
  unsigned int b = __float_as_uint(v);
  return (b + 0x7FFFu + ((b >> 16) & 1u)) >> 16;
}
__device__ __forceinline__ unsigned int pk2bf(float lo, float hi) {
  __hip_bfloat162 h2 = __float22bfloat162_rn(make_float2(lo, hi));  // v_cvt_pk_bf16_f32, RNE
  return *reinterpret_cast<unsigned int*>(&h2);
}
__device__ __forceinline__ bf16x8 ldb8(const unsigned short* p) {
  return *(const bf16x8*)p;
}

// ---------------------------------------------------------------------------
// Kernel 0: weight prep + transposes. (unchanged)
// ---------------------------------------------------------------------------
__global__ __launch_bounds__(256) void k_prep(
    const float* __restrict__ w1, const float* __restrict__ w2,
    const float* __restrict__ w3, const float* __restrict__ linw,
    const float* __restrict__ wih0, const float* __restrict__ whh0,
    const float* __restrict__ wih1, const float* __restrict__ whh1,
    unsigned short* __restrict__ w1eh, unsigned short* __restrict__ w1el,
    unsigned short* __restrict__ w2h, unsigned short* __restrict__ w2l,
    unsigned short* __restrict__ w3h, unsigned short* __restrict__ w3l,
    unsigned short* __restrict__ linwh, unsigned short* __restrict__ linwl,
    unsigned short* __restrict__ wih0h, unsigned short* __restrict__ wih0l,
    float* __restrict__ whh0T, float* __restrict__ wih1T,
    float* __restrict__ whh1T) {
  const int e = blockIdx.x * 256 + threadIdx.x;
  if (e >= 264960) {
    int e5 = e - 264960;
    int m = e5 >> 16, r = e5 & 65535;
    int k = r >> 9, j = r & 511;
    const float* src = (m == 0) ? whh0 : ((m == 1) ? wih1 : whh1);
    float* dst = (m == 0) ? whh0T : ((m == 1) ? wih1T : whh1T);
    dst[r] = src[j * 128 + k];
    return;
  }
  float v;
  unsigned short* dh;
  unsigned short* dl;
  int di;
  if (e < 20480) {
    int cc = e / 5120, rem = e - cc * 5120;
    int c2 = rem / 160, r = rem - c2 * 160;
    int tap = r >> 5, c1l = r & 31;
    v = w2[c2 * 640 + (cc * 32 + c1l) * 5 + tap];
    dh = w2h; dl = w2l; di = e;
  } else if (e < 25600) {
    int e2 = e - 20480;
    int c3 = e2 / 160, r = e2 - c3 * 160;
    int tap = r >> 5, c2 = r & 31;
    v = w3[c3 * 160 + c2 * 5 + tap];
    dh = w3h; dl = w3l; di = e2;
  } else if (e < 198400) {
    int e3 = e - 25600;
    v = linw[e3];
    dh = linwh; dl = linwl; di = e3;
  } else if (e < 263936) {
    int e4 = e - 198400;
    int g = e4 >> 7, k = e4 & 127;
    v = (k < 100) ? wih0[g * 100 + k] : 0.f;
    dh = wih0h; dl = wih0l; di = e4;
  } else {
    int i = e - 263936;
    int c1 = i >> 3, j = i & 7;
    v = (j < 5) ? w1[c1 * 5 + j] : 0.f;
    dh = w1eh; dl = w1el; di = i;
  }
  unsigned int hb = bf16rne(v);
  float hf = __uint_as_float(hb << 16);
  unsigned int lb = bf16rne(v - hf);
  dh[di] = (unsigned short)hb;
  dl[di] = (unsigned short)lb;
}

// ---------------------------------------------------------------------------
// Kernel 1: conv1 (fp32, thread=position) + conv2 (MFMA) + conv3 (MFMA).
// REVERTED to round-10 structure (1 block/n, 512 thr, 48.6 KB LDS,
// 3 blocks/CU -- measured 113 us; round-11 2-block split regressed to 191).
// NEW: bf16 pair-packs via v_cvt_pk_bf16_f32 (__float22bfloat162_rn),
// bit-identical RNE, ~8 VALU -> 1 per pair.
// ---------------------------------------------------------------------------
__global__ __launch_bounds__(512) void k_conv123(
    const float* __restrict__ X, const float* __restrict__ w1,
    const unsigned short* __restrict__ w2h, const unsigned short* __restrict__ w2l,
    const unsigned short* __restrict__ w3h, const unsigned short* __restrict__ w3l,
    unsigned short* __restrict__ s3g) {
  __shared__ __align__(16) float Xs[1504];
  __shared__ __align__(16) unsigned int AhU[10640];  // [532 rows][20 u32]

  const int n = blockIdx.x;
  const int tid = threadIdx.x;
  const int lane = tid & 63;
  const int w = tid >> 6;        // 0..7
  const int l15 = lane & 15;
  const int cg = lane >> 4;

  const float* Xn = X + (size_t)n * 1500;
  for (int i = tid; i < 1500; i += 512) Xs[i] = Xn[i];
  if (tid < 4) Xs[1500 + tid] = 0.f;
  for (int i = tid; i < 640; i += 512) AhU[10000 + i] = 0u;  // rows 500..531
  __syncthreads();

  // hoisted conv1 window (position = tid)
  float x0 = 0.f, x1 = 0.f, x2 = 0.f, x3 = 0.f, x4 = 0.f;
  if (tid < 500) {
    const float* xp = Xs + 3 * tid;
    x0 = xp[0]; x1 = xp[1]; x2 = xp[2]; x3 = xp[3]; x4 = xp[4];
  }

  f32x4 acc2[2][2];
#pragma unroll
  for (int a = 0; a < 2; ++a)
#pragma unroll
    for (int m = 0; m < 2; ++m) acc2[a][m] = (f32x4){0.f, 0.f, 0.f, 0.f};

  for (int cc = 0; cc < 4; ++cc) {  // 4 chunks of 32 c1
    __syncthreads();                // previous chunk's conv2 reads done
    // ---- conv1: all 32 c1 of this chunk for position tid ----
    if (tid < 500) {
      const float* wc = w1 + cc * 160;  // uniform address -> s_load
      unsigned int rowbuf[16];
#pragma unroll
      for (int p = 0; p < 16; ++p) {
        const float* wa = wc + 10 * p;
        float vA = fmaf(x4, wa[4], fmaf(x3, wa[3], fmaf(x2, wa[2], fmaf(x1, wa[1], x0 * wa[0]))));
        float vB = fmaf(x4, wa[9], fmaf(x3, wa[8], fmaf(x2, wa[7], fmaf(x1, wa[6], x0 * wa[5]))));
        vA = fmaxf(vA, 0.01f * vA);  // leaky == max(v, 0.01v)
        vB = fmaxf(vB, 0.01f * vB);
        rowbuf[p] = pk2bf(vA, vB);
      }
#pragma unroll
      for (int q = 0; q < 4; ++q)
        *(uint4*)(&AhU[tid * 20 + 4 * q]) = *(uint4*)(&rowbuf[4 * q]);
    }
    __syncthreads();
    // ---- conv2 MFMA over this chunk ----
    const unsigned short* w2hB = w2h + cc * 5120;
    const unsigned short* w2lB = w2l + cc * 5120;
#pragma unroll
    for (int tap = 0; tap < 5; ++tap) {
      const int wc = tap * 32 + cg * 8;
      bf16x8 ah0 = ldb8(w2hB + l15 * 160 + wc);
      bf16x8 ah1 = ldb8(w2hB + (l15 + 16) * 160 + wc);
      bf16x8 al0 = ldb8(w2lB + l15 * 160 + wc);
      bf16x8 al1 = ldb8(w2lB + (l15 + 16) * 160 + wc);
      {  // n-tile w
        bf16x8 bfr = ldb8((const unsigned short*)AhU + (3 * (w * 16 + l15) + tap) * 40 + cg * 8);
        acc2[0][0] = __builtin_amdgcn_mfma_f32_16x16x32_bf16(ah0, bfr, acc2[0][0], 0, 0, 0);
        acc2[0][0] = __builtin_amdgcn_mfma_f32_16x16x32_bf16(al0, bfr, acc2[0][0], 0, 0, 0);
        acc2[0][1] = __builtin_amdgcn_mfma_f32_16x16x32_bf16(ah1, bfr, acc2[0][1], 0, 0, 0);
        acc2[0][1] = __builtin_amdgcn_mfma_f32_16x16x32_bf16(al1, bfr, acc2[0][1], 0, 0, 0);
      }
      if (w < 3) {  // n-tile 8+w
        int nt = 8 + w;
        bf16x8 bfr = ldb8((const unsigned short*)AhU + (3 * (nt * 16 + l15) + tap) * 40 + cg * 8);
        acc2[1][0] = __builtin_amdgcn_mfma_f32_16x16x32_bf16(ah0, bfr, acc2[1][0], 0, 0, 0);
        acc2[1][0] = __builtin_amdgcn_mfma_f32_16x16x32_bf16(al0, bfr, acc2[1][0], 0, 0, 0);
        acc2[1][1] = __builtin_amdgcn_mfma_f32_16x16x32_bf16(ah1, bfr, acc2[1][1], 0, 0, 0);
        acc2[1][1] = __builtin_amdgcn_mfma_f32_16x16x32_bf16(al1, bfr, acc2[1][1], 0, 0, 0);
      }
    }
  }
  __syncthreads();  // all conv2 reads of AhU done
  // A3 (aliases AhU): rows = l2; zero pad rows 176..195
  for (int i = tid; i < 400; i += 512) AhU[176 * 20 + i] = 0u;
#pragma unroll
  for (int nti = 0; nti < 2; ++nti) {
    int nt = (nti == 0) ? w : (8 + w);
    if (nti == 0 || w < 3) {
      int l2 = nt * 16 + l15;
#pragma unroll
      for (int mt = 0; mt < 2; ++mt) {
#pragma unroll
        for (int j = 0; j < 2; ++j) {
          float e0 = leakyf(acc2[nti][mt][2 * j]);
          float e1 = leakyf(acc2[nti][mt][2 * j + 1]);
          AhU[l2 * 20 + mt * 8 + cg * 2 + j] = pk2bf(e0, e1);
        }
      }
    }
  }
  __syncthreads();
  // conv3 MFMA: waves 0..3 (l3 tile = w)
  if (w < 4) {
    f32x4 a3[2];
    a3[0] = (f32x4){0.f, 0.f, 0.f, 0.f};
    a3[1] = (f32x4){0.f, 0.f, 0.f, 0.f};
#pragma unroll
    for (int tap = 0; tap < 5; ++tap) {
      const int wc = tap * 32 + cg * 8;
      bf16x8 wh0 = ldb8(w3h + l15 * 160 + wc);
      bf16x8 wh1 = ldb8(w3h + (l15 + 16) * 160 + wc);
      bf16x8 wl0 = ldb8(w3l + l15 * 160 + wc);
      bf16x8 wl1 = ldb8(w3l + (l15 + 16) * 160 + wc);
      bf16x8 bfr = ldb8((const unsigned short*)AhU + (3 * (w * 16 + l15) + tap) * 40 + cg * 8);
      a3[0] = __builtin_amdgcn_mfma_f32_16x16x32_bf16(wh0, bfr, a3[0], 0, 0, 0);
      a3[0] = __builtin_amdgcn_mfma_f32_16x16x32_bf16(wl0, bfr, a3[0], 0, 0, 0);
      a3[1] = __builtin_amdgcn_mfma_f32_16x16x32_bf16(wh1, bfr, a3[1], 0, 0, 0);
      a3[1] = __builtin_amdgcn_mfma_f32_16x16x32_bf16(wl1, bfr, a3[1], 0, 0, 0);
    }
    int l3 = w * 16 + l15;
    if (l3 < L3OUT) {
#pragma unroll
      for (int mt = 0; mt < 2; ++mt) {
#pragma unroll
        for (int r = 0; r < 4; ++r) {
          int c3 = mt * 16 + cg * 4 + r;
          s3g[(size_t)n * FLAT_ + c3 * L3OUT + l3] = (unsigned short)bf16rne(leakyf(a3[mt][r]));
        }
      }
    }
  }
}

// ---------------------------------------------------------------------------
// Kernel 2: FUSED fe + xg0. (unchanged from round 10)
// ---------------------------------------------------------------------------
__global__ __launch_bounds__(448) void k_gemm_fx(
    const unsigned short* __restrict__ s3g,
    const unsigned short* __restrict__ linwh, const unsigned short* __restrict__ linwl,
    const unsigned short* __restrict__ wih0h, const unsigned short* __restrict__ wih0l,
    float* __restrict__ xg0) {
  __shared__ __align__(16) unsigned short fehS[16][136];
  __shared__ __align__(16) unsigned short felS[16][136];

  const int m0 = blockIdx.x * 16;
  const int tid = threadIdx.x;
  const int lane = tid & 63;
  const int w = tid >> 6;
  const int l15 = lane & 15;
  const int cg = lane >> 4;

  if (tid < 192) {
    int r = tid / 12, c = tid - r * 12;
    ((unsigned int*)&fehS[r][112])[c] = 0u;
    ((unsigned int*)&felS[r][112])[c] = 0u;
  }

  int brow = w * 16 + l15;
  if (brow > 99) brow = 99;
  const unsigned short* ap = s3g + (size_t)(m0 + l15) * FLAT_ + cg * 8;
  const unsigned short* bhp = linwh + (size_t)brow * FLAT_ + cg * 8;
  const unsigned short* blp = linwl + (size_t)brow * FLAT_ + cg * 8;

  f32x4 acc = (f32x4){0.f, 0.f, 0.f, 0.f};
#pragma unroll 6
  for (int ks = 0; ks < 54; ++ks) {
    bf16x8 af = ldb8(ap + ks * 32);
    bf16x8 bh = ldb8(bhp + ks * 32);
    bf16x8 bl = ldb8(blp + ks * 32);
    acc = __builtin_amdgcn_mfma_f32_16x16x32_bf16(af, bh, acc, 0, 0, 0);
    acc = __builtin_amdgcn_mfma_f32_16x16x32_bf16(af, bl, acc, 0, 0, 0);
  }
  const int jcol = w * 16 + l15;
#pragma unroll
  for (int r = 0; r < 4; ++r) {
    float v = acc[r];
    unsigned int hb = bf16rne(v);
    float hf = __uint_as_float(hb << 16);
    unsigned int lb = bf16rne(v - hf);
    fehS[cg * 4 + r][jcol] = (unsigned short)hb;
    felS[cg * 4 + r][jcol] = (unsigned short)lb;
  }
  __syncthreads();

#pragma unroll
  for (int nt0 = 0; nt0 < 5; ++nt0) {
    int nt = w + 7 * nt0;
    if (nt < 32) {
      f32x4 a = (f32x4){0.f, 0.f, 0.f, 0.f};
#pragma unroll
      for (int ks = 0; ks < 4; ++ks) {
        bf16x8 ah = ldb8(&fehS[l15][ks * 32 + cg * 8]);
        bf16x8 al = ldb8(&felS[l15][ks * 32 + cg * 8]);
        int br = nt * 16 + l15;
        bf16x8 bh = ldb8(wih0h + (size_t)br * 128 + ks * 32 + cg * 8);
        bf16x8 bl = ldb8(wih0l + (size_t)br * 128 + ks * 32 + cg * 8);
        a = __builtin_amdgcn_mfma_f32_16x16x32_bf16(ah, bh, a, 0, 0, 0);
        a = __builtin_amdgcn_mfma_f32_16x16x32_bf16(ah, bl, a, 0, 0, 0);
        a = __builtin_amdgcn_mfma_f32_16x16x32_bf16(al, bh, a, 0, 0, 0);
      }
#pragma unroll
      for (int r = 0; r < 4; ++r)
        xg0[(size_t)(m0 + cg * 4 + r) * 512 + nt * 16 + l15] = a[r];
    }
  }
}

// ---------------------------------------------------------------------------
// Kernel 3: LSTM layer 0 -- K-sliced dot + NEW 3-phase activation split:
// phase A: 512 thr dot partials -> ps; phase B: 512 thr (gate = tid) combine
// + x + activation (1 transcendental/thread, wave-uniform kind) -> gs;
// phase C: 128 thr state update (1 tanh). 3 barriers/step.
// ---------------------------------------------------------------------------
__global__ __launch_bounds__(512) void k_lstm0(
    const float* __restrict__ xg0, const float* __restrict__ whh0T,
    const int* __restrict__ lengths, float* __restrict__ hs1) {
  __shared__ __align__(16) float h0s[H_];
  __shared__ float ps[16 * 128];
  __shared__ float gs[512];
  const int b = blockIdx.x;
  const int tid = threadIdx.x;
  const int ks = tid >> 7;   // K-slice in phase A; gate group in phase B
  const int jj = tid & 127;
  float w[4][32];
#pragma unroll
  for (int kk = 0; kk < 32; ++kk) {
#pragma unroll
    for (int q = 0; q < 4; ++q)
      w[q][kk] = whh0T[(ks * 32 + kk) * 512 + q * 128 + jj];
  }
  if (tid < H_) h0s[tid] = 0.f;
  float c = 0.f;
  const int len = lengths[b];
  float xcur = xg0[(size_t)(b * T_) * 512 + tid];
  __syncthreads();
  for (int t = 0; t < len; ++t) {
    float xnxt = (t + 1 < len) ? xg0[(size_t)(b * T_ + t + 1) * 512 + tid] : 0.f;
    float p0 = 0.f, p1 = 0.f, p2 = 0.f, p3 = 0.f;
#pragma unroll
    for (int k4 = 0; k4 < 8; ++k4) {
      float4 hv = *(const float4*)(h0s + ks * 32 + k4 * 4);
      p0 = fmaf(hv.x, w[0][k4 * 4], fmaf(hv.y, w[0][k4 * 4 + 1], fmaf(hv.z, w[0][k4 * 4 + 2], fmaf(hv.w, w[0][k4 * 4 + 3], p0))));
      p1 = fmaf(hv.x, w[1][k4 * 4], fmaf(hv.y, w[1][k4 * 4 + 1], fmaf(hv.z, w[1][k4 * 4 + 2], fmaf(hv.w, w[1][k4 * 4 + 3], p1))));
      p2 = fmaf(hv.x, w[2][k4 * 4], fmaf(hv.y, w[2][k4 * 4 + 1], fmaf(hv.z, w[2][k4 * 4 + 2], fmaf(hv.w, w[2][k4 * 4 + 3], p2))));
      p3 = fmaf(hv.x, w[3][k4 * 4], fmaf(hv.y, w[3][k4 * 4 + 1], fmaf(hv.z, w[3][k4 * 4 + 2], fmaf(hv.w, w[3][k4 * 4 + 3], p3))));
    }
    ps[(ks * 4 + 0) * 128 + jj] = p0;
    ps[(ks * 4 + 1) * 128 + jj] = p1;
    ps[(ks * 4 + 2) * 128 + jj] = p2;
    ps[(ks * 4 + 3) * 128 + jj] = p3;
    __syncthreads();
    // phase B: gate index = tid = ks*128 + jj
    {
      float gsum = xcur + ((ps[(0 * 4 + ks) * 128 + jj] + ps[(1 * 4 + ks) * 128 + jj]) +
                           (ps[(2 * 4 + ks) * 128 + jj] + ps[(3 * 4 + ks) * 128 + jj]));
      gs[tid] = (ks == 2) ? tanhf(gsum) : sigmoidf_(gsum);
    }
    __syncthreads();
    if (tid < H_) {
      float ig = gs[jj];
      float fg = gs[128 + jj];
      float gt = gs[256 + jj];
      float og = gs[384 + jj];
      c = fg * c + ig * gt;
      float hn = og * tanhf(c);
      h0s[jj] = hn;
      hs1[((size_t)(b * T_ + t)) * H_ + jj] = hn;
    }
    __syncthreads();
    xcur = xnxt;
  }
}

// ---------------------------------------------------------------------------
// Kernel 4: xg1 = hs1 @ wih1^T. (unchanged)
// ---------------------------------------------------------------------------
__global__ __launch_bounds__(512) void k_xg1(
    const float* __restrict__ hs1, const float* __restrict__ wih1T,
    float* __restrict__ xg1) {
  __shared__ __align__(16) float hsS[8][128];
  const int r0 = blockIdx.x * 8;
  const int tid = threadIdx.x;
  for (int i = tid; i < 8 * 128; i += 512) ((float*)hsS)[i] = hs1[(size_t)r0 * 128 + i];
  __syncthreads();
  float acc[8] = {0.f, 0.f, 0.f, 0.f, 0.f, 0.f, 0.f, 0.f};
#pragma unroll 4
  for (int k4 = 0; k4 < 32; ++k4) {
    float w0 = wih1T[(4 * k4 + 0) * 512 + tid];
    float w1v = wih1T[(4 * k4 + 1) * 512 + tid];
    float w2v = wih1T[(4 * k4 + 2) * 512 + tid];
    float w3v = wih1T[(4 * k4 + 3) * 512 + tid];
#pragma unroll
    for (int i = 0; i < 8; ++i) {
      float4 h = *(const float4*)(&hsS[i][4 * k4]);
      acc[i] += h.x * w0 + h.y * w1v + h.z * w2v + h.w * w3v;
    }
  }
#pragma unroll
  for (int i = 0; i < 8; ++i) xg1[((size_t)(r0 + i)) * 512 + tid] = acc[i];
}

// ---------------------------------------------------------------------------
// Kernel 5: LSTM layer 1 + FC tail -- same 3-phase structure.
// ---------------------------------------------------------------------------
__global__ __launch_bounds__(512) void k_lstm1(
    const float* __restrict__ xg1, const float* __restrict__ whh1T,
    const float* __restrict__ fc1, const float* __restrict__ fc2,
    const int* __restrict__ lengths, float* __restrict__ out) {
  __shared__ __align__(16) float h1s[H_];
  __shared__ float ps[16 * 128];
  __shared__ float gs[512];
  __shared__ float tmp10[10];
  const int b = blockIdx.x;
  const int tid = threadIdx.x;
  const int ks = tid >> 7;
  const int jj = tid & 127;
  float w[4][32];
#pragma unroll
  for (int kk = 0; kk < 32; ++kk) {
#pragma unroll
    for (int q = 0; q < 4; ++q)
      w[q][kk] = whh1T[(ks * 32 + kk) * 512 + q * 128 + jj];
  }
  if (tid < H_) h1s[tid] = 0.f;
  float c = 0.f;
  const int len = lengths[b];
  float xcur = xg1[(size_t)(b * T_) * 512 + tid];
  __syncthreads();
  for (int t = 0; t < len; ++t) {
    float xnxt = (t + 1 < len) ? xg1[(size_t)(b * T_ + t + 1) * 512 + tid] : 0.f;
    float p0 = 0.f, p1 = 0.f, p2 = 0.f, p3 = 0.f;
#pragma unroll
    for (int k4 = 0; k4 < 8; ++k4) {
      float4 hv = *(const float4*)(h1s + ks * 32 + k4 * 4);
      p0 = fmaf(hv.x, w[0][k4 * 4], fmaf(hv.y, w[0][k4 * 4 + 1], fmaf(hv.z, w[0][k4 * 4 + 2], fmaf(hv.w, w[0][k4 * 4 + 3], p0))));
      p1 = fmaf(hv.x, w[1][k4 * 4], fmaf(hv.y, w[1][k4 * 4 + 1], fmaf(hv.z, w[1][k4 * 4 + 2], fmaf(hv.w, w[1][k4 * 4 + 3], p1))));
      p2 = fmaf(hv.x, w[2][k4 * 4], fmaf(hv.y, w[2][k4 * 4 + 1], fmaf(hv.z, w[2][k4 * 4 + 2], fmaf(hv.w, w[2][k4 * 4 + 3], p2))));
      p3 = fmaf(hv.x, w[3][k4 * 4], fmaf(hv.y, w[3][k4 * 4 + 1], fmaf(hv.z, w[3][k4 * 4 + 2], fmaf(hv.w, w[3][k4 * 4 + 3], p3))));
    }
    ps[(ks * 4 + 0) * 128 + jj] = p0;
    ps[(ks * 4 + 1) * 128 + jj] = p1;
    ps[(ks * 4 + 2) * 128 + jj] = p2;
    ps[(ks * 4 + 3) * 128 + jj] = p3;
    __syncthreads();
    {
      float gsum = xcur + ((ps[(0 * 4 + ks) * 128 + jj] + ps[(1 * 4 + ks) * 128 + jj]) +
                           (ps[(2 * 4 + ks) * 128 + jj] + ps[(3 * 4 + ks) * 128 + jj]));
      gs[tid] = (ks == 2) ? tanhf(gsum) : sigmoidf_(gsum);
    }
    __syncthreads();
    if (tid < H_) {
      float ig = gs[jj];
      float fg = gs[128 + jj];
      float gt = gs[256 + jj];
      float og = gs[384 + jj];
      c = fg * c + ig * gt;
      float hn = og * tanhf(c);
      h1s[jj] = hn;
    }
    __syncthreads();
    xcur = xnxt;
  }
  if (tid < 10) {
    const float* fr = fc1 + tid * H_;
    float s = 0.f;
#pragma unroll 4
    for (int k = 0; k < H_; ++k) s += h1s[k] * fr[k];
    tmp10[tid] = leakyf(s);
  }
  __syncthreads();
  if (tid < 2) {
    const float* fr = fc2 + tid * 10;
    float s = 0.f;
#pragma unroll
    for (int j = 0; j < 10; ++j) s += tmp10[j] * fr[j];
    out[b * 2 + tid] = leakyf(s);
  }
}

extern "C" void kernel_launch(void* const* d_in, const int* in_sizes, int n_in,
                              void* d_out, int out_size, void* d_ws, size_t ws_size,
                              hipStream_t stream) {
  const float* X = (const float*)d_in[0];
  const int* lengths = (const int*)d_in[1];
  const float* w1 = (const float*)d_in[2];
  const float* w2 = (const float*)d_in[3];
  const float* w3 = (const float*)d_in[4];
  const float* linw = (const float*)d_in[5];
  const float* wih0 = (const float*)d_in[6];
  const float* whh0 = (const float*)d_in[7];
  const float* wih1 = (const float*)d_in[8];
  const float* whh1 = (const float*)d_in[9];
  const float* fc1 = (const float*)d_in[10];
  const float* fc2 = (const float*)d_in[11];

  char* wsb = (char*)d_ws;
  size_t off = 0;
  auto alloc = [&](size_t bytes) {
    char* p = wsb + off;
    off += (bytes + 511) & ~(size_t)511;
    return p;
  };
  unsigned short* s3g = (unsigned short*)alloc(2048 * 1728 * 2);
  float* xg0 = (float*)alloc(2048 * 512 * 4);
  unsigned short* w1eh = (unsigned short*)alloc(1024 * 2);
  unsigned short* w1el = (unsigned short*)alloc(1024 * 2);
  unsigned short* w2h = (unsigned short*)alloc(20480 * 2);
  unsigned short* w2l = (unsigned short*)alloc(20480 * 2);
  unsigned short* w3h = (unsigned short*)alloc(5120 * 2);
  unsigned short* w3l = (unsigned short*)alloc(5120 * 2);
  unsigned short* linwh = (unsigned short*)alloc(172800 * 2);
  unsigned short* linwl = (unsigned short*)alloc(172800 * 2);
  unsigned short* wih0h = (unsigned short*)alloc(65536 * 2);
  unsigned short* wih0l = (unsigned short*)alloc(65536 * 2);
  float* whh0T = (float*)alloc(65536 * 4);
  float* wih1T = (float*)alloc(65536 * 4);
  float* whh1T = (float*)alloc(65536 * 4);
  float* hs1 = (float*)alloc(262144 * 4);
  float* xg1 = (float*)alloc(2048 * 512 * 4);

  k_prep<<<1803, 256, 0, stream>>>(w1, w2, w3, linw, wih0, whh0, wih1, whh1,
                                   w1eh, w1el, w2h, w2l, w3h, w3l,
                                   linwh, linwl, wih0h, wih0l,
                                   whh0T, wih1T, whh1T);
  k_conv123<<<2048, 512, 0, stream>>>(X, w1, w2h, w2l, w3h, w3l, s3g);
  k_gemm_fx<<<128, 448, 0, stream>>>(s3g, linwh, linwl, wih0h, wih0l, xg0);
  k_lstm0<<<32, 512, 0, stream>>>(xg0, whh0T, lengths, hs1);
  k_xg1<<<256, 512, 0, stream>>>(hs1, wih1T, xg1);
  k_lstm1<<<32, 512, 0, stream>>>(xg1, whh1T, fc1, fc2, lengths, (float*)d_out);
}